// Round 1
// baseline (382.822 us; speedup 1.0000x reference)
//
#include <hip/hip_runtime.h>
#include <math.h>

#define G 8
#define Hd 256
#define Wd 256
#define HW (Hd * Wd)

// ---------------------------------------------------------------------------
// Kernel 1: one block per (b,c) image. Builds 4 GLCM histograms in LDS,
// computes the 4 texture features per angle, runs the tiny MLP, writes
// (sigmoid(diag)+1) to wplus[bc].
//
// Pair semantics (d=1, angles 0, pi/4, pi/2, 3pi/4), zero-padded borders:
//   angle0: (q(y,x), q(y,x-1))
//   angle1: (q(y,x), q(y+1,x-1))
//   angle2: (q(y,x), q(y+1,x))
//   angle3: (q(y,x), q(y+1,x+1))
// Out-of-bounds neighbor -> float 0 -> bin 0 (pad is applied pre-quantize,
// and quantize(0)=0, so the histogram total is always H*W).
// ---------------------------------------------------------------------------
__global__ __launch_bounds__(256) void glcm_kernel(const float* __restrict__ x,
                                                   const float* __restrict__ W1,
                                                   const float* __restrict__ W2,
                                                   float* __restrict__ wplus) {
    // qt: 17 staged rows, cols 0..257 represent x = -1..256 (edges = 0).
    // Row stride 260 bytes (65 words) -> bank stride 1 word per row: a wave's
    // 4 rows x 16 segment-lanes map 2 lanes/bank (free, m136).
    __shared__ unsigned char qt[17][260];
    __shared__ unsigned int hist[4 * 64];   // [angle][q*8+qs]
    __shared__ float feats_s[16];
    __shared__ float h_s[16];

    const int t = threadIdx.x;
    const int bc = blockIdx.x;              // b*64 + c
    const float* img = x + (size_t)bc * HW;

    hist[t] = 0u;                           // 256 entries, 256 threads
    __syncthreads();

    const int r_row = t >> 4;               // 0..15: row within tile
    const int xs = (t & 15) << 4;           // 0,16,...,240: column segment

    for (int tile = 0; tile < 16; ++tile) {
        const int r0 = tile << 4;
        // Stage 17 rows x 256 cols (quantized), coalesced global loads.
        for (int idx = t; idx < 17 * 256; idx += 256) {
            const int r = idx >> 8;
            const int c = idx & 255;
            const int y = r0 + r;
            const float v = (y < Hd) ? img[y * Wd + c] : 0.0f;
            qt[r][c + 1] = (unsigned char)(int)(v * 7.0f);
        }
        if (t < 17) { qt[t][0] = 0; qt[t][257] = 0; }
        __syncthreads();

        // 16 pixels per thread, rolling window: 2 LDS reads + 4 atomics / px.
        int a0 = qt[r_row][xs];             // q(y, x-1)
        int a1 = qt[r_row + 1][xs];         // q(y+1, x-1)
        int a2 = qt[r_row + 1][xs + 1];     // q(y+1, x)
        #pragma unroll
        for (int k = 0; k < 16; ++k) {
            const int cx = xs + k;
            const int qc = qt[r_row][cx + 1];       // q(y, x)
            const int a3 = qt[r_row + 1][cx + 2];   // q(y+1, x+1)
            const int qc8 = qc << 3;
            atomicAdd(&hist[  0 + qc8 + a0], 1u);
            atomicAdd(&hist[ 64 + qc8 + a1], 1u);
            atomicAdd(&hist[128 + qc8 + a2], 1u);
            atomicAdd(&hist[192 + qc8 + a3], 1u);
            a0 = qc; a1 = a2; a2 = a3;
        }
        __syncthreads();
    }

    // ---- features: wave w handles angle w (64 bins = 64 lanes) ----
    float csum, hsum, esum, rsum;
    {
        const int a = t >> 6;
        const int bin = t & 63;
        const float p = (float)hist[a * 64 + bin] * (1.0f / 65536.0f);
        const int i = bin >> 3, j = bin & 7;
        const int dij = i - j;
        const int adij = dij < 0 ? -dij : dij;
        csum = (float)(dij * dij) * p;
        hsum = p / (float)(1 + adij);
        esum = p * p;
        rsum = ((float)i - 3.5f) * ((float)j - 3.5f) * p;
    }
    #pragma unroll
    for (int m = 1; m < 64; m <<= 1) {
        csum += __shfl_xor(csum, m, 64);
        hsum += __shfl_xor(hsum, m, 64);
        esum += __shfl_xor(esum, m, 64);
        rsum += __shfl_xor(rsum, m, 64);
    }
    if ((t & 63) == 0) {
        const int a = t >> 6;
        feats_s[a * 4 + 0] = csum;
        feats_s[a * 4 + 1] = hsum;
        feats_s[a * 4 + 2] = esum;
        // I_STD^2 + 1e-6 with I_STD = sqrt(6) (ddof=1 std of arange(8))
        feats_s[a * 4 + 3] = rsum * (1.0f / 6.000001f);
    }
    __syncthreads();

    // ---- MLP: h = relu(feats @ W1); z = h @ W2[:, c]; w = sigmoid(z) ----
    if (t < 16) {
        float acc = 0.0f;
        #pragma unroll
        for (int f = 0; f < 16; ++f) acc += feats_s[f] * W1[f * 16 + t];
        h_s[t] = acc > 0.0f ? acc : 0.0f;
    }
    __syncthreads();
    if (t == 0) {
        const int c = bc & 63;
        float z = 0.0f;
        #pragma unroll
        for (int k = 0; k < 16; ++k) z += h_s[k] * W2[k * 64 + c];
        const float w = 1.0f / (1.0f + expf(-z));
        wplus[bc] = w + 1.0f;
    }
}

// ---------------------------------------------------------------------------
// Kernel 2: out = x * wplus[bc], float4-vectorized. 16384 float4 per (b,c),
// blocks of 256 -> bc uniform per block (blockIdx>>6) -> scalar broadcast.
// ---------------------------------------------------------------------------
__global__ __launch_bounds__(256) void scale_kernel(const float4* __restrict__ x4,
                                                    const float* __restrict__ wplus,
                                                    float4* __restrict__ out4) {
    const int idx = blockIdx.x * 256 + threadIdx.x;
    const float w = wplus[blockIdx.x >> 6];
    float4 v = x4[idx];
    v.x *= w; v.y *= w; v.z *= w; v.w *= w;
    out4[idx] = v;
}

extern "C" void kernel_launch(void* const* d_in, const int* in_sizes, int n_in,
                              void* d_out, int out_size, void* d_ws, size_t ws_size,
                              hipStream_t stream) {
    const float* x  = (const float*)d_in[0];
    const float* W1 = (const float*)d_in[1];   // (16,16) row-major
    const float* W2 = (const float*)d_in[2];   // (16,64) row-major
    float* wplus = (float*)d_ws;               // 512 floats of scratch
    float* out = (float*)d_out;

    glcm_kernel<<<512, 256, 0, stream>>>(x, W1, W2, wplus);

    const int n4 = out_size / 4;               // 8388608 float4
    scale_kernel<<<n4 / 256, 256, 0, stream>>>((const float4*)x, wplus,
                                               (float4*)out);
}

// Round 2
// 309.694 us; speedup vs baseline: 1.2361x; 1.2361x over previous
//
#include <hip/hip_runtime.h>
#include <math.h>

#define G 8
#define Hd 256
#define Wd 256
#define HW (Hd * Wd)
#define RS 268   // qt row stride (bytes): 67 words, odd -> conflict-free byte reads

// ---------------------------------------------------------------------------
// Kernel 1: one block per (b,c) image. Ballot-popcount GLCM: lane L of each
// wave owns bin L (i=L>>3 matches q, j=L&7 matches qs) of a per-wave private
// histogram kept in registers. Zero LDS atomics in the hot loop.
//
// Pair semantics (d=1, angles 0, pi/4, pi/2, 3pi/4), zero-padded borders:
//   angle0: (q(y,x), q(y,x-1))
//   angle1: (q(y,x), q(y+1,x-1))
//   angle2: (q(y,x), q(y+1,x))
//   angle3: (q(y,x), q(y+1,x+1))
// Out-of-bounds neighbor -> float 0 -> bin 0 (histogram total = H*W).
// ---------------------------------------------------------------------------
__global__ __launch_bounds__(256) void glcm_kernel(const float* __restrict__ x,
                                                   const float* __restrict__ W1,
                                                   const float* __restrict__ W2,
                                                   float* __restrict__ wplus) {
    __shared__ unsigned char qt[17 * RS];   // cols 4..259 = x 0..255; col 3/260 = pad
    __shared__ unsigned int hist[4 * 64];   // [angle][i*8+j], merged at the end
    __shared__ float feats_s[16];
    __shared__ float h_s[16];

    const int t = threadIdx.x;
    const int bc = blockIdx.x;              // b*64 + c
    const float4* img4 = (const float4*)(x + (size_t)bc * HW);

    hist[t] = 0u;
    if (t < 17) { qt[t * RS + 3] = 0; qt[t * RS + 260] = 0; }

    const int lane = t & 63;
    // XNOR selectors: bin L matches q bits via lane bits 3..5, qs via bits 0..2.
    const unsigned long long E0 = (lane & 8)  ? 0ull : ~0ull;
    const unsigned long long E1 = (lane & 16) ? 0ull : ~0ull;
    const unsigned long long E2 = (lane & 32) ? 0ull : ~0ull;
    const unsigned long long F0 = (lane & 1)  ? 0ull : ~0ull;
    const unsigned long long F1 = (lane & 2)  ? 0ull : ~0ull;
    const unsigned long long F2 = (lane & 4)  ? 0ull : ~0ull;

    unsigned int cnt0 = 0, cnt1 = 0, cnt2 = 0, cnt3 = 0;

    const int r_row = t >> 4;               // 0..15: row within tile
    const int xs = (t & 15) << 4;           // 0..240: column segment
    __syncthreads();

    for (int tile = 0; tile < 16; ++tile) {
        const int r0 = tile << 4;
        // Stage 17 rows x 256 cols quantized: float4 load -> packed u32 write.
        for (int idx = t; idx < 17 * 64; idx += 256) {
            const int r = idx >> 6;
            const int c = idx & 63;
            const int y = r0 + r;
            float4 v;
            if (y < Hd) v = img4[y * 64 + c];
            else { v.x = 0.f; v.y = 0.f; v.z = 0.f; v.w = 0.f; }
            const unsigned int p =  (unsigned int)(int)(v.x * 7.0f)
                                 | ((unsigned int)(int)(v.y * 7.0f) << 8)
                                 | ((unsigned int)(int)(v.z * 7.0f) << 16)
                                 | ((unsigned int)(int)(v.w * 7.0f) << 24);
            *(unsigned int*)&qt[r * RS + 4 + (c << 2)] = p;
        }
        __syncthreads();

        const unsigned char* rowc = &qt[r_row * RS + 4 + xs];
        const unsigned char* rown = rowc + RS;
        int a0 = rowc[-1];                  // q(y, x-1)
        int a1 = rown[-1];                  // q(y+1, x-1)
        int a2 = rown[0];                   // q(y+1, x)
        #pragma unroll
        for (int k = 0; k < 16; ++k) {
            const int qc = rowc[k];         // q(y, x)
            const int a3 = rown[k + 1];     // q(y+1, x+1)
            const unsigned long long B0 = __ballot(qc & 1);
            const unsigned long long B1 = __ballot(qc & 2);
            const unsigned long long B2 = __ballot(qc & 4);
            const unsigned long long Mi = (B0 ^ E0) & (B1 ^ E1) & (B2 ^ E2);
            {
                const unsigned long long C0 = __ballot(a0 & 1);
                const unsigned long long C1 = __ballot(a0 & 2);
                const unsigned long long C2 = __ballot(a0 & 4);
                cnt0 += __popcll(Mi & (C0 ^ F0) & (C1 ^ F1) & (C2 ^ F2));
            }
            {
                const unsigned long long C0 = __ballot(a1 & 1);
                const unsigned long long C1 = __ballot(a1 & 2);
                const unsigned long long C2 = __ballot(a1 & 4);
                cnt1 += __popcll(Mi & (C0 ^ F0) & (C1 ^ F1) & (C2 ^ F2));
            }
            {
                const unsigned long long C0 = __ballot(a2 & 1);
                const unsigned long long C1 = __ballot(a2 & 2);
                const unsigned long long C2 = __ballot(a2 & 4);
                cnt2 += __popcll(Mi & (C0 ^ F0) & (C1 ^ F1) & (C2 ^ F2));
            }
            {
                const unsigned long long C0 = __ballot(a3 & 1);
                const unsigned long long C1 = __ballot(a3 & 2);
                const unsigned long long C2 = __ballot(a3 & 4);
                cnt3 += __popcll(Mi & (C0 ^ F0) & (C1 ^ F1) & (C2 ^ F2));
            }
            a0 = qc; a1 = a2; a2 = a3;
        }
        __syncthreads();
    }

    // ---- merge 4 per-wave register histograms: 16 wave-atomics total ----
    atomicAdd(&hist[  0 + lane], cnt0);
    atomicAdd(&hist[ 64 + lane], cnt1);
    atomicAdd(&hist[128 + lane], cnt2);
    atomicAdd(&hist[192 + lane], cnt3);
    __syncthreads();

    // ---- features: wave w handles angle w (64 bins = 64 lanes) ----
    float csum, hsum, esum, rsum;
    {
        const int a = t >> 6;
        const int bin = t & 63;
        const float p = (float)hist[a * 64 + bin] * (1.0f / 65536.0f);
        const int i = bin >> 3, j = bin & 7;
        const int dij = i - j;
        const int adij = dij < 0 ? -dij : dij;
        csum = (float)(dij * dij) * p;
        hsum = p / (float)(1 + adij);
        esum = p * p;
        rsum = ((float)i - 3.5f) * ((float)j - 3.5f) * p;
    }
    #pragma unroll
    for (int m = 1; m < 64; m <<= 1) {
        csum += __shfl_xor(csum, m, 64);
        hsum += __shfl_xor(hsum, m, 64);
        esum += __shfl_xor(esum, m, 64);
        rsum += __shfl_xor(rsum, m, 64);
    }
    if ((t & 63) == 0) {
        const int a = t >> 6;
        feats_s[a * 4 + 0] = csum;
        feats_s[a * 4 + 1] = hsum;
        feats_s[a * 4 + 2] = esum;
        // I_STD^2 + 1e-6 with I_STD = sqrt(6) (ddof=1 std of arange(8))
        feats_s[a * 4 + 3] = rsum * (1.0f / 6.000001f);
    }
    __syncthreads();

    // ---- MLP: h = relu(feats @ W1); z = h @ W2[:, c]; w = sigmoid(z) ----
    if (t < 16) {
        float acc = 0.0f;
        #pragma unroll
        for (int f = 0; f < 16; ++f) acc += feats_s[f] * W1[f * 16 + t];
        h_s[t] = acc > 0.0f ? acc : 0.0f;
    }
    __syncthreads();
    if (t == 0) {
        const int c = bc & 63;
        float z = 0.0f;
        #pragma unroll
        for (int k = 0; k < 16; ++k) z += h_s[k] * W2[k * 64 + c];
        const float w = 1.0f / (1.0f + expf(-z));
        wplus[bc] = w + 1.0f;
    }
}

// ---------------------------------------------------------------------------
// Kernel 2: out = x * wplus[bc], float4-vectorized; bc uniform per block.
// ---------------------------------------------------------------------------
__global__ __launch_bounds__(256) void scale_kernel(const float4* __restrict__ x4,
                                                    const float* __restrict__ wplus,
                                                    float4* __restrict__ out4) {
    const int idx = blockIdx.x * 256 + threadIdx.x;
    const float w = wplus[blockIdx.x >> 6];
    float4 v = x4[idx];
    v.x *= w; v.y *= w; v.z *= w; v.w *= w;
    out4[idx] = v;
}

extern "C" void kernel_launch(void* const* d_in, const int* in_sizes, int n_in,
                              void* d_out, int out_size, void* d_ws, size_t ws_size,
                              hipStream_t stream) {
    const float* x  = (const float*)d_in[0];
    const float* W1 = (const float*)d_in[1];   // (16,16) row-major
    const float* W2 = (const float*)d_in[2];   // (16,64) row-major
    float* wplus = (float*)d_ws;               // 512 floats of scratch
    float* out = (float*)d_out;

    glcm_kernel<<<512, 256, 0, stream>>>(x, W1, W2, wplus);

    const int n4 = out_size / 4;               // 8388608 float4
    scale_kernel<<<n4 / 256, 256, 0, stream>>>((const float4*)x, wplus,
                                               (float4*)out);
}

// Round 3
// 272.323 us; speedup vs baseline: 1.4058x; 1.1372x over previous
//
#include <hip/hip_runtime.h>
#include <math.h>

#define G 8
#define Hd 256
#define Wd 256
#define HW (Hd * Wd)

// ---------------------------------------------------------------------------
// Kernel 1: one block (1024 thr = 16 waves) per (b,c) image. Row-ballot GLCM:
// a wave's 64 lanes = 64 consecutive columns. Per row: 3 ballots give the
// bitplane masks of q(y, ·); neighbor masks for all 4 angles are scalar
// shifts of the row masks (carry bits from the adjacent 64-col segment).
// Lane L owns bin L (i = L>>3, j = L&7): per-lane XNOR-select + popcount.
// No LDS staging, no hot-loop atomics, no per-tile barriers.
//
// Pair semantics (d=1, angles 0, pi/4, pi/2, 3pi/4), zero-padded borders:
//   angle0: (q(y,x), q(y,x-1))   angle1: (q(y,x), q(y+1,x-1))
//   angle2: (q(y,x), q(y+1,x))   angle3: (q(y,x), q(y+1,x+1))
// OOB neighbor -> 0.0f -> bin j=0 (shift-in zeros / zero row masks give
// exactly this: all-zero bitplanes XNOR-match j==0).
// ---------------------------------------------------------------------------
__global__ __launch_bounds__(1024) void glcm_kernel(const float* __restrict__ x,
                                                    const float* __restrict__ W1,
                                                    const float* __restrict__ W2,
                                                    float* __restrict__ wplus) {
    __shared__ unsigned int hist[4 * 64];   // [angle][i*8+j]
    __shared__ float feats_s[16];
    __shared__ float h_s[16];

    const int t = threadIdx.x;
    const int bc = blockIdx.x;              // b*64 + c
    const float* img = x + (size_t)bc * HW;

    if (t < 256) hist[t] = 0u;

    const int lane = t & 63;
    const int wv = t >> 6;                  // 0..15
    const int r0 = wv << 4;                 // first owned row

    // XNOR selectors: lane bit set -> selector 0 (keep mask bit), else ~0.
    const unsigned long long E0 = (lane & 8)  ? 0ull : ~0ull;
    const unsigned long long E1 = (lane & 16) ? 0ull : ~0ull;
    const unsigned long long E2 = (lane & 32) ? 0ull : ~0ull;
    const unsigned long long F0 = (lane & 1)  ? 0ull : ~0ull;
    const unsigned long long F1 = (lane & 2)  ? 0ull : ~0ull;
    const unsigned long long F2 = (lane & 4)  ? 0ull : ~0ull;

    unsigned int cnt0 = 0, cnt1 = 0, cnt2 = 0, cnt3 = 0;

    unsigned long long B[4][3];             // row bitplanes per 64-col segment
    unsigned long long Mi_prev[4];          // i-select masks of previous row

    auto load_ballots = [&](int y) {
        #pragma unroll
        for (int s = 0; s < 4; ++s) {
            const float v = img[y * Wd + (s << 6) + lane];
            const int q = (int)(v * 7.0f);
            B[s][0] = __ballot(q & 1);
            B[s][1] = __ballot(q & 2);
            B[s][2] = __ballot(q & 4);
        }
    };
    auto mk_mi = [&](unsigned long long b0, unsigned long long b1,
                     unsigned long long b2) {
        return (b0 ^ E0) & (b1 ^ E1) & (b2 ^ E2);
    };
    auto mk_mj = [&](unsigned long long b0, unsigned long long b1,
                     unsigned long long b2) {
        return (b0 ^ F0) & (b1 ^ F1) & (b2 ^ F2);
    };

    // ---- first owned row: angle0 only; seed Mi_prev ----
    load_ballots(r0);
    #pragma unroll
    for (int s = 0; s < 4; ++s) {
        const unsigned long long bl0 = (B[s][0] << 1) | (s ? (B[s-1][0] >> 63) : 0ull);
        const unsigned long long bl1 = (B[s][1] << 1) | (s ? (B[s-1][1] >> 63) : 0ull);
        const unsigned long long bl2 = (B[s][2] << 1) | (s ? (B[s-1][2] >> 63) : 0ull);
        const unsigned long long mi = mk_mi(B[s][0], B[s][1], B[s][2]);
        cnt0 += __popcll(mi & mk_mj(bl0, bl1, bl2));
        Mi_prev[s] = mi;
    }

    // ---- rows r0+1 .. r0+15: angles1-3 for row above, angle0 for self ----
    for (int yy = 1; yy < 16; ++yy) {
        load_ballots(r0 + yy);
        #pragma unroll
        for (int s = 0; s < 4; ++s) {
            const unsigned long long bl0 = (B[s][0] << 1) | (s ? (B[s-1][0] >> 63) : 0ull);
            const unsigned long long bl1 = (B[s][1] << 1) | (s ? (B[s-1][1] >> 63) : 0ull);
            const unsigned long long bl2 = (B[s][2] << 1) | (s ? (B[s-1][2] >> 63) : 0ull);
            const unsigned long long br0 = (B[s][0] >> 1) | (s < 3 ? (B[s+1][0] << 63) : 0ull);
            const unsigned long long br1 = (B[s][1] >> 1) | (s < 3 ? (B[s+1][1] << 63) : 0ull);
            const unsigned long long br2 = (B[s][2] >> 1) | (s < 3 ? (B[s+1][2] << 63) : 0ull);
            const unsigned long long mjl = mk_mj(bl0, bl1, bl2);
            const unsigned long long mj0 = mk_mj(B[s][0], B[s][1], B[s][2]);
            const unsigned long long mjr = mk_mj(br0, br1, br2);
            cnt1 += __popcll(Mi_prev[s] & mjl);
            cnt2 += __popcll(Mi_prev[s] & mj0);
            cnt3 += __popcll(Mi_prev[s] & mjr);
            const unsigned long long mi = mk_mi(B[s][0], B[s][1], B[s][2]);
            cnt0 += __popcll(mi & mjl);
            Mi_prev[s] = mi;
        }
    }

    // ---- boundary row r0+16 (next wave's first row, or zero pad) ----
    if (r0 + 16 < Hd) {
        load_ballots(r0 + 16);
    } else {
        #pragma unroll
        for (int s = 0; s < 4; ++s) { B[s][0] = 0; B[s][1] = 0; B[s][2] = 0; }
    }
    #pragma unroll
    for (int s = 0; s < 4; ++s) {
        const unsigned long long bl0 = (B[s][0] << 1) | (s ? (B[s-1][0] >> 63) : 0ull);
        const unsigned long long bl1 = (B[s][1] << 1) | (s ? (B[s-1][1] >> 63) : 0ull);
        const unsigned long long bl2 = (B[s][2] << 1) | (s ? (B[s-1][2] >> 63) : 0ull);
        const unsigned long long br0 = (B[s][0] >> 1) | (s < 3 ? (B[s+1][0] << 63) : 0ull);
        const unsigned long long br1 = (B[s][1] >> 1) | (s < 3 ? (B[s+1][1] << 63) : 0ull);
        const unsigned long long br2 = (B[s][2] >> 1) | (s < 3 ? (B[s+1][2] << 63) : 0ull);
        cnt1 += __popcll(Mi_prev[s] & mk_mj(bl0, bl1, bl2));
        cnt2 += __popcll(Mi_prev[s] & mk_mj(B[s][0], B[s][1], B[s][2]));
        cnt3 += __popcll(Mi_prev[s] & mk_mj(br0, br1, br2));
    }

    __syncthreads();                        // hist init visible
    atomicAdd(&hist[  0 + lane], cnt0);
    atomicAdd(&hist[ 64 + lane], cnt1);
    atomicAdd(&hist[128 + lane], cnt2);
    atomicAdd(&hist[192 + lane], cnt3);
    __syncthreads();

    // ---- features: wave a (t<256) handles angle a; 64 bins = 64 lanes ----
    if (t < 256) {
        float csum, hsum, esum, rsum;
        {
            const int a = t >> 6;
            const int bin = t & 63;
            const float p = (float)hist[a * 64 + bin] * (1.0f / 65536.0f);
            const int i = bin >> 3, j = bin & 7;
            const int dij = i - j;
            const int adij = dij < 0 ? -dij : dij;
            csum = (float)(dij * dij) * p;
            hsum = p / (float)(1 + adij);
            esum = p * p;
            rsum = ((float)i - 3.5f) * ((float)j - 3.5f) * p;
        }
        #pragma unroll
        for (int m = 1; m < 64; m <<= 1) {
            csum += __shfl_xor(csum, m, 64);
            hsum += __shfl_xor(hsum, m, 64);
            esum += __shfl_xor(esum, m, 64);
            rsum += __shfl_xor(rsum, m, 64);
        }
        if ((t & 63) == 0) {
            const int a = t >> 6;
            feats_s[a * 4 + 0] = csum;
            feats_s[a * 4 + 1] = hsum;
            feats_s[a * 4 + 2] = esum;
            // I_STD^2 + 1e-6, I_STD = sqrt(6) (ddof=1 std of arange(8))
            feats_s[a * 4 + 3] = rsum * (1.0f / 6.000001f);
        }
    }
    __syncthreads();

    // ---- MLP: h = relu(feats @ W1); z = h @ W2[:, c]; w = sigmoid(z) ----
    if (t < 16) {
        float acc = 0.0f;
        #pragma unroll
        for (int f = 0; f < 16; ++f) acc += feats_s[f] * W1[f * 16 + t];
        h_s[t] = acc > 0.0f ? acc : 0.0f;
    }
    __syncthreads();
    if (t == 0) {
        const int c = bc & 63;
        float z = 0.0f;
        #pragma unroll
        for (int k = 0; k < 16; ++k) z += h_s[k] * W2[k * 64 + c];
        const float w = 1.0f / (1.0f + expf(-z));
        wplus[bc] = w + 1.0f;
    }
}

// ---------------------------------------------------------------------------
// Kernel 2: out = x * wplus[bc], float4-vectorized; bc uniform per block.
// ---------------------------------------------------------------------------
__global__ __launch_bounds__(256) void scale_kernel(const float4* __restrict__ x4,
                                                    const float* __restrict__ wplus,
                                                    float4* __restrict__ out4) {
    const int idx = blockIdx.x * 256 + threadIdx.x;
    const float w = wplus[blockIdx.x >> 6];
    float4 v = x4[idx];
    v.x *= w; v.y *= w; v.z *= w; v.w *= w;
    out4[idx] = v;
}

extern "C" void kernel_launch(void* const* d_in, const int* in_sizes, int n_in,
                              void* d_out, int out_size, void* d_ws, size_t ws_size,
                              hipStream_t stream) {
    const float* x  = (const float*)d_in[0];
    const float* W1 = (const float*)d_in[1];   // (16,16) row-major
    const float* W2 = (const float*)d_in[2];   // (16,64) row-major
    float* wplus = (float*)d_ws;               // 512 floats of scratch
    float* out = (float*)d_out;

    glcm_kernel<<<512, 1024, 0, stream>>>(x, W1, W2, wplus);

    const int n4 = out_size / 4;               // 8388608 float4
    scale_kernel<<<n4 / 256, 256, 0, stream>>>((const float4*)x, wplus,
                                               (float4*)out);
}